// Round 6
// baseline (54.456 us; speedup 1.0000x reference)
//
#include <hip/hip_runtime.h>
#include <math.h>

#define HW 16384
#define NPROJ 100
#define NB 8
#define NCH 32
#define CHLEN 512
#define EPSV 1e-6f

__device__ inline float4 add4(float4 a, float4 b) {
    return make_float4(a.x + b.x, a.y + b.y, a.z + b.z, a.w + b.w);
}
__device__ inline float4 sub4(float4 a, float4 b) {
    return make_float4(a.x - b.x, a.y - b.y, a.z - b.z, a.w - b.w);
}
__device__ inline float4 shfl_up4(float4 v, int off) {
    return make_float4(__shfl_up(v.x, off), __shfl_up(v.y, off),
                       __shfl_up(v.z, off), __shfl_up(v.w, off));
}

// Stage 1: per-(batch, chunk) partials: Xs = x0+x1+x2 (stored), sum(Xs), sum(y0),
// chunk max/argmax of x0 (first-occurrence). Block 0 zeroes the output.
__global__ __launch_bounds__(256) void partial_kernel(const float* __restrict__ X,
                                                      const float* __restrict__ Y,
                                                      float* __restrict__ Xs,
                                                      float* __restrict__ Pmax,
                                                      int* __restrict__ Pidx,
                                                      float* __restrict__ Psx,
                                                      float* __restrict__ Psy,
                                                      float* __restrict__ out) {
    const int blk = blockIdx.x;
    const int b = blk >> 5, c = blk & 31;
    const int tid = threadIdx.x, lane = tid & 63, wid = tid >> 6;
    if (blk == 0 && tid == 0) out[0] = 0.0f;  // consumed only by wproj (later kernel)
    const float* xb = X + (size_t)b * 3 * HW;
    const float* yb = Y + (size_t)b * 3 * HW;
    const int base = c * CHLEN;

    float mv = -INFINITY;
    int mi = 0;
    float sx = 0.0f, sy = 0.0f;
#pragma unroll
    for (int k = 0; k < 2; ++k) {
        int p = base + k * 256 + tid;
        float x0 = xb[p], x1 = xb[HW + p], x2 = xb[2 * HW + p], y0 = yb[p];
        float s = x0 + x1 + x2;
        Xs[(size_t)b * HW + p] = s;
        sx += s;
        sy += y0;
        if (x0 > mv) { mv = x0; mi = p; }   // strict > keeps earliest p
    }
#pragma unroll
    for (int off = 32; off > 0; off >>= 1) {
        float ov = __shfl_down(mv, off);
        int oi = __shfl_down(mi, off);
        sx += __shfl_down(sx, off);
        sy += __shfl_down(sy, off);
        if (ov > mv || (ov == mv && oi < mi)) { mv = ov; mi = oi; }
    }
    __shared__ float lmv[4], lsx[4], lsy[4];
    __shared__ int lmi[4];
    if (lane == 0) { lmv[wid] = mv; lmi[wid] = mi; lsx[wid] = sx; lsy[wid] = sy; }
    __syncthreads();
    if (tid == 0) {
        for (int w = 1; w < 4; ++w) {
            if (lmv[w] > lmv[0] || (lmv[w] == lmv[0] && lmi[w] < lmi[0])) {
                lmv[0] = lmv[w];
                lmi[0] = lmi[w];
            }
            lsx[0] += lsx[w];
            lsy[0] += lsy[w];
        }
        Pmax[blk] = lmv[0];
        Pidx[blk] = lmi[0];
        Psx[blk] = lsx[0];
        Psy[blk] = lsy[0];
    }
}

// Stage 2 (combine folded in): every block redundantly reduces the 8x32 partials,
// then builds Z[p][b] = (Xs+fix)*invX - Y0*invY, pixel-major float8 (32B/pixel).
__global__ __launch_bounds__(256) void zprep_kernel(const float* __restrict__ Pmax,
                                                    const int* __restrict__ Pidx,
                                                    const float* __restrict__ Psx,
                                                    const float* __restrict__ Psy,
                                                    const float* __restrict__ Xs,
                                                    const float* __restrict__ Y,
                                                    float* __restrict__ Z) {
    __shared__ float sInvX[8], sInvY[8], sFa[8];
    __shared__ int sFi[8];
    const int tid = threadIdx.x;
    const int c = tid & 31;
    {
        const int b = tid >> 5;
        float mv = Pmax[tid];
        int mi = Pidx[tid];
        float sx = Psx[tid];
        float sy = Psy[tid];
#pragma unroll
        for (int off = 16; off > 0; off >>= 1) {
            float ov = __shfl_down(mv, off, 32);
            int oi = __shfl_down(mi, off, 32);
            float osx = __shfl_down(sx, off, 32);
            float osy = __shfl_down(sy, off, 32);
            if (ov > mv || (ov == mv && oi < mi)) { mv = ov; mi = oi; }
            sx += osx;
            sy += osy;
        }
        if (c == 0) {
            float fa = (mv < EPSV) ? (EPSV - mv) : 0.0f;
            sFa[b] = fa;
            sFi[b] = mi;
            sInvX[b] = 1.0f / (sx + fa);
            sInvY[b] = 1.0f / sy;
        }
    }
    __syncthreads();
    const int p = blockIdx.x * 256 + tid;
    float z[8];
#pragma unroll
    for (int b = 0; b < 8; ++b) {
        float s = Xs[(size_t)b * HW + p];
        if (p == sFi[b]) s += sFa[b];
        z[b] = s * sInvX[b] - Y[(size_t)b * 3 * HW + p] * sInvY[b];
    }
    float4* zp = (float4*)(Z + (size_t)p * 8);
    zp[0] = make_float4(z[0], z[1], z[2], z[3]);
    zp[1] = make_float4(z[4], z[5], z[6], z[7]);
}

// One block per projection. Phase 1: analytic ranksort -> transposed id table in
// LDS (sidT[m][1024], conflict-free phase-2 reads). Phase 2: single-chunk
// register-resident 8-channel scan (2 halves of float4), Z gathered exactly
// once; pc recomputed from ids (no float LDS reads, no spc buffer).
__global__ __launch_bounds__(1024) void wproj_kernel(const float* __restrict__ proj,
                                                     const float* __restrict__ Z,
                                                     float* __restrict__ out) {
    __shared__ unsigned short sidT[16 * 1024];  // 32 KiB
    __shared__ int c_t[255];
    __shared__ unsigned char e_t[255];
    __shared__ float4 lw[16];
    __shared__ float lred[16];

    const int jp = blockIdx.x;
    const int tid = threadIdx.x, lane = tid & 63, wid = tid >> 6;
    float a = proj[jp];
    float b = proj[NPROJ + jp];
    float inv = 1.0f / sqrtf(a * a + b * b);
    const float an = a * inv, bn = b * inv;
    const float ap = fabsf(an), bp = fabsf(bn);
    const bool flipi = (an < 0.0f), flipj = (bn < 0.0f);

    // ---- phase 1: ranksort into transposed LDS table ----
    if (bp == 0.0f) {
        for (int t = tid; t < HW; t += 1024) {
            int i2 = t >> 7, j2 = t & 127;
            int ii = flipi ? 127 - i2 : i2;
            int jj = flipj ? 127 - j2 : j2;
            sidT[(t & 15) * 1024 + (t >> 4)] = (unsigned short)(ii * 128 + jj);
        }
    } else {
        if (tid < 255) {
            int d = tid - 127;
            double v = (double)d * ((double)ap / (double)bp);
            double cv = ceil(v);
            e_t[tid] = (cv == v) ? 1 : 0;
            c_t[tid] = (int)fmin(fmax(cv, -128.0), 129.0);
        }
        __syncthreads();
        if (tid < 128) {
            const int j2 = tid;
            const int jj = flipj ? 127 - j2 : j2;
            int wsum = 0;
#pragma unroll 8
            for (int dd = 0; dd <= 127; ++dd)
                wsum += min(max(c_t[dd] + j2, 0), 128);
            int tsum = 0;
            for (int i2 = 0; i2 < 128; ++i2) {
                if (i2 > 0) {
                    int dd_new = i2 + 127;
                    int dd_old = i2 - 1;
                    int cn = c_t[dd_new];
                    wsum += min(max(cn + j2, 0), 128);
                    wsum -= min(max(c_t[dd_old] + j2, 0), 128);
                    if (e_t[dd_new]) {
                        int tj = j2 + cn;
                        if (tj >= 0 && tj < 128) tsum++;
                    }
                }
                int pos = wsum + tsum;
                int ii = flipi ? 127 - i2 : i2;
                sidT[(pos & 15) * 1024 + (pos >> 4)] =
                    (unsigned short)(ii * 128 + jj);
            }
        }
    }
    __syncthreads();

    // ---- phase 2: each thread owns 16 consecutive sorted positions ----
    int ids[17];
#pragma unroll
    for (int m = 0; m < 16; ++m) ids[m] = (int)sidT[m * 1024 + tid];
    ids[16] = (tid < 1023) ? (int)sidT[tid + 1] : ids[15];  // next thread's first

    float acc = 0.0f;
#pragma unroll 1
    for (int half = 0; half < 2; ++half) {
        // gather + in-register prefix (float4 = 4 channels)
        float4 zv[16];
#pragma unroll
        for (int m = 0; m < 16; ++m)
            zv[m] = *(const float4*)(Z + (size_t)ids[m] * 8 + half * 4);
#pragma unroll
        for (int m = 1; m < 16; ++m) zv[m] = add4(zv[m], zv[m - 1]);
        const float4 tot = zv[15];

        // wave-level inclusive scan of per-thread totals
        float4 ia = tot;
#pragma unroll
        for (int off = 1; off < 64; off <<= 1) {
            float4 ua = shfl_up4(ia, off);
            if (lane >= off) ia = add4(ia, ua);
        }
        if (lane == 63) lw[wid] = ia;
        __syncthreads();
        float4 offv = sub4(ia, tot);  // exclusive within wave
        for (int w = 0; w < wid; ++w) offv = add4(offv, lw[w]);  // broadcast reads

        // integral with rolling pc recompute
        float pc_cur = (float)(ids[0] >> 7) * an + (float)(ids[0] & 127) * bn;
#pragma unroll
        for (int m = 0; m < 16; ++m) {
            int idn = ids[m + 1];
            float pc_nxt = (float)(idn >> 7) * an + (float)(idn & 127) * bn;
            float4 cx = add4(offv, zv[m]);
            float s4 = fabsf(cx.x) + fabsf(cx.y) + fabsf(cx.z) + fabsf(cx.w);
            acc += s4 * (pc_nxt - pc_cur);
            pc_cur = pc_nxt;
        }
        __syncthreads();  // protect lw reuse in next half
    }

    // block reduce
#pragma unroll
    for (int off = 32; off > 0; off >>= 1) acc += __shfl_down(acc, off);
    if (lane == 0) lred[wid] = acc;
    __syncthreads();
    if (tid == 0) {
        float r = 0.0f;
        for (int w = 0; w < 16; ++w) r += lred[w];
        atomicAdd(out, r * (1.0f / NPROJ));
    }
}

extern "C" void kernel_launch(void* const* d_in, const int* in_sizes, int n_in,
                              void* d_out, int out_size, void* d_ws, size_t ws_size,
                              hipStream_t stream) {
    const float* X = (const float*)d_in[0];
    const float* Y = (const float*)d_in[1];
    const float* proj = (const float*)d_in[2];
    float* out = (float*)d_out;

    char* ws = (char*)d_ws;
    size_t off = 0;
    float* Xs = (float*)(ws + off);     off += (size_t)NB * HW * sizeof(float);
    float* Z = (float*)(ws + off);      off += (size_t)NB * HW * sizeof(float);
    float* Pmax = (float*)(ws + off);   off += NB * NCH * sizeof(float);
    int* Pidx = (int*)(ws + off);       off += NB * NCH * sizeof(int);
    float* Psx = (float*)(ws + off);    off += NB * NCH * sizeof(float);
    float* Psy = (float*)(ws + off);    off += NB * NCH * sizeof(float);

    partial_kernel<<<NB * NCH, 256, 0, stream>>>(X, Y, Xs, Pmax, Pidx, Psx, Psy, out);
    zprep_kernel<<<HW / 256, 256, 0, stream>>>(Pmax, Pidx, Psx, Psy, Xs, Y, Z);
    wproj_kernel<<<NPROJ, 1024, 0, stream>>>(proj, Z, out);
}

// Round 7
// 43.344 us; speedup vs baseline: 1.2564x; 1.2564x over previous
//
#include <hip/hip_runtime.h>
#include <math.h>

#define HW 16384
#define NPROJ 100
#define NB 8
#define NCH 32
#define CHLEN 512
#define EPSV 1e-6f

__device__ inline float4 add4(float4 a, float4 b) {
    return make_float4(a.x + b.x, a.y + b.y, a.z + b.z, a.w + b.w);
}
__device__ inline float4 sub4(float4 a, float4 b) {
    return make_float4(a.x - b.x, a.y - b.y, a.z - b.z, a.w - b.w);
}
__device__ inline float4 shfl_up4(float4 v, int off) {
    return make_float4(__shfl_up(v.x, off), __shfl_up(v.y, off),
                       __shfl_up(v.z, off), __shfl_up(v.w, off));
}

// Stage 1: per-(batch, chunk) partials: Xs = x0+x1+x2 (stored), sum(Xs), sum(y0),
// chunk max/argmax of x0 (first-occurrence). Block 0 zeroes the output.
__global__ __launch_bounds__(256) void partial_kernel(const float* __restrict__ X,
                                                      const float* __restrict__ Y,
                                                      float* __restrict__ Xs,
                                                      float* __restrict__ Pmax,
                                                      int* __restrict__ Pidx,
                                                      float* __restrict__ Psx,
                                                      float* __restrict__ Psy,
                                                      float* __restrict__ out) {
    const int blk = blockIdx.x;
    const int b = blk >> 5, c = blk & 31;
    const int tid = threadIdx.x, lane = tid & 63, wid = tid >> 6;
    if (blk == 0 && tid == 0) out[0] = 0.0f;  // consumed only by wproj (later kernel)
    const float* xb = X + (size_t)b * 3 * HW;
    const float* yb = Y + (size_t)b * 3 * HW;
    const int base = c * CHLEN;

    float mv = -INFINITY;
    int mi = 0;
    float sx = 0.0f, sy = 0.0f;
#pragma unroll
    for (int k = 0; k < 2; ++k) {
        int p = base + k * 256 + tid;
        float x0 = xb[p], x1 = xb[HW + p], x2 = xb[2 * HW + p], y0 = yb[p];
        float s = x0 + x1 + x2;
        Xs[(size_t)b * HW + p] = s;
        sx += s;
        sy += y0;
        if (x0 > mv) { mv = x0; mi = p; }   // strict > keeps earliest p
    }
#pragma unroll
    for (int off = 32; off > 0; off >>= 1) {
        float ov = __shfl_down(mv, off);
        int oi = __shfl_down(mi, off);
        sx += __shfl_down(sx, off);
        sy += __shfl_down(sy, off);
        if (ov > mv || (ov == mv && oi < mi)) { mv = ov; mi = oi; }
    }
    __shared__ float lmv[4], lsx[4], lsy[4];
    __shared__ int lmi[4];
    if (lane == 0) { lmv[wid] = mv; lmi[wid] = mi; lsx[wid] = sx; lsy[wid] = sy; }
    __syncthreads();
    if (tid == 0) {
        for (int w = 1; w < 4; ++w) {
            if (lmv[w] > lmv[0] || (lmv[w] == lmv[0] && lmi[w] < lmi[0])) {
                lmv[0] = lmv[w];
                lmi[0] = lmi[w];
            }
            lsx[0] += lsx[w];
            lsy[0] += lsy[w];
        }
        Pmax[blk] = lmv[0];
        Pidx[blk] = lmi[0];
        Psx[blk] = lsx[0];
        Psy[blk] = lsy[0];
    }
}

// Stage 2 (combine folded in): every block redundantly reduces the 8x32 partials,
// then builds Z[p][b] = (Xs+fix)*invX - Y0*invY, pixel-major float8 (32B/pixel).
__global__ __launch_bounds__(256) void zprep_kernel(const float* __restrict__ Pmax,
                                                    const int* __restrict__ Pidx,
                                                    const float* __restrict__ Psx,
                                                    const float* __restrict__ Psy,
                                                    const float* __restrict__ Xs,
                                                    const float* __restrict__ Y,
                                                    float* __restrict__ Z) {
    __shared__ float sInvX[8], sInvY[8], sFa[8];
    __shared__ int sFi[8];
    const int tid = threadIdx.x;
    const int c = tid & 31;
    {
        const int b = tid >> 5;
        float mv = Pmax[tid];
        int mi = Pidx[tid];
        float sx = Psx[tid];
        float sy = Psy[tid];
#pragma unroll
        for (int off = 16; off > 0; off >>= 1) {
            float ov = __shfl_down(mv, off, 32);
            int oi = __shfl_down(mi, off, 32);
            float osx = __shfl_down(sx, off, 32);
            float osy = __shfl_down(sy, off, 32);
            if (ov > mv || (ov == mv && oi < mi)) { mv = ov; mi = oi; }
            sx += osx;
            sy += osy;
        }
        if (c == 0) {
            float fa = (mv < EPSV) ? (EPSV - mv) : 0.0f;
            sFa[b] = fa;
            sFi[b] = mi;
            sInvX[b] = 1.0f / (sx + fa);
            sInvY[b] = 1.0f / sy;
        }
    }
    __syncthreads();
    const int p = blockIdx.x * 256 + tid;
    float z[8];
#pragma unroll
    for (int b = 0; b < 8; ++b) {
        float s = Xs[(size_t)b * HW + p];
        if (p == sFi[b]) s += sFa[b];
        z[b] = s * sInvX[b] - Y[(size_t)b * 3 * HW + p] * sInvY[b];
    }
    float4* zp = (float4*)(Z + (size_t)p * 8);
    zp[0] = make_float4(z[0], z[1], z[2], z[3]);
    zp[1] = make_float4(z[4], z[5], z[6], z[7]);
}

// One block per projection. Phase 1: analytic ranksort (8 i2-groups x 128 j2,
// all 1024 threads active) -> transposed id table in LDS. Phase 2: 8-channel
// scan with zv[16] float4 in registers (launch_bounds(1024,4) => 128-VGPR cap,
// no spill); ids re-read from conflict-free LDS; pc recomputed from ids.
__global__ __launch_bounds__(1024, 4) void wproj_kernel(const float* __restrict__ proj,
                                                        const float* __restrict__ Z,
                                                        float* __restrict__ out) {
    __shared__ unsigned short sidT[16 * 1024];  // 32 KiB
    __shared__ int c_t[255];
    __shared__ unsigned char e_t[255];
    __shared__ float4 lw[16];
    __shared__ float lred[16];

    const int jp = blockIdx.x;
    const int tid = threadIdx.x, lane = tid & 63, wid = tid >> 6;
    float a = proj[jp];
    float b = proj[NPROJ + jp];
    float inv = 1.0f / sqrtf(a * a + b * b);
    const float an = a * inv, bn = b * inv;
    const float ap = fabsf(an), bp = fabsf(bn);
    const bool flipi = (an < 0.0f), flipj = (bn < 0.0f);

    // ---- phase 1: ranksort into transposed LDS table ----
    if (bp == 0.0f) {
        for (int t = tid; t < HW; t += 1024) {
            int i2 = t >> 7, j2 = t & 127;
            int ii = flipi ? 127 - i2 : i2;
            int jj = flipj ? 127 - j2 : j2;
            sidT[(t & 15) * 1024 + (t >> 4)] = (unsigned short)(ii * 128 + jj);
        }
    } else {
        if (tid < 255) {
            int d = tid - 127;
            double v = (double)d * ((double)ap / (double)bp);
            double cv = ceil(v);
            e_t[tid] = (cv == v) ? 1 : 0;
            c_t[tid] = (int)fmin(fmax(cv, -128.0), 129.0);
        }
        __syncthreads();
        {
            const int j2 = tid & 127;
            const int g = tid >> 7;          // 0..7, each covers 16 rows of i2
            const int i2s = g * 16;
            const int jj = flipj ? 127 - j2 : j2;

            // window init at i2 = i2s: dd in [i2s, i2s+127]
            int wsum = 0;
#pragma unroll 8
            for (int q = 0; q < 128; ++q)
                wsum += min(max(c_t[i2s + q] + j2, 0), 128);
            // tie-count prefix: steps i2' = 1..i2s
            int tsum = 0;
            for (int i2p = 1; i2p <= i2s; ++i2p) {
                if (e_t[i2p + 127]) {
                    int tj = j2 + c_t[i2p + 127];
                    if (tj >= 0 && tj < 128) tsum++;
                }
            }
            for (int q = 0; q < 16; ++q) {
                int i2 = i2s + q;
                if (q > 0) {
                    int dd_new = i2 + 127;
                    int dd_old = i2 - 1;
                    int cn = c_t[dd_new];
                    wsum += min(max(cn + j2, 0), 128);
                    wsum -= min(max(c_t[dd_old] + j2, 0), 128);
                    if (e_t[dd_new]) {
                        int tj = j2 + cn;
                        if (tj >= 0 && tj < 128) tsum++;
                    }
                }
                int pos = wsum + tsum;
                int ii = flipi ? 127 - i2 : i2;
                sidT[(pos & 15) * 1024 + (pos >> 4)] =
                    (unsigned short)(ii * 128 + jj);
            }
        }
    }
    __syncthreads();

    // ---- phase 2: thread owns positions [16*tid, 16*tid+15] ----
    float acc = 0.0f;
#pragma unroll 1
    for (int half = 0; half < 2; ++half) {
        float4 zv[16];
#pragma unroll
        for (int m = 0; m < 16; ++m) {
            int id = (int)sidT[m * 1024 + tid];
            zv[m] = *(const float4*)(Z + (size_t)id * 8 + half * 4);
        }
#pragma unroll
        for (int m = 1; m < 16; ++m) zv[m] = add4(zv[m], zv[m - 1]);
        const float4 tot = zv[15];

        float4 ia = tot;
#pragma unroll
        for (int off = 1; off < 64; off <<= 1) {
            float4 ua = shfl_up4(ia, off);
            if (lane >= off) ia = add4(ia, ua);
        }
        if (lane == 63) lw[wid] = ia;
        __syncthreads();
        float4 offv = sub4(ia, tot);  // exclusive within wave
        for (int w = 0; w < wid; ++w) offv = add4(offv, lw[w]);

        int id_cur = (int)sidT[tid];  // position 16*tid
        float pc_cur = (float)(id_cur >> 7) * an + (float)(id_cur & 127) * bn;
#pragma unroll
        for (int m = 0; m < 16; ++m) {
            int idn;
            if (m < 15) idn = (int)sidT[(m + 1) * 1024 + tid];
            else idn = (tid < 1023) ? (int)sidT[tid + 1] : id_cur;
            float pc_nxt = (float)(idn >> 7) * an + (float)(idn & 127) * bn;
            float4 cx = add4(offv, zv[m]);
            float s4 = fabsf(cx.x) + fabsf(cx.y) + fabsf(cx.z) + fabsf(cx.w);
            acc += s4 * (pc_nxt - pc_cur);
            pc_cur = pc_nxt;
        }
        __syncthreads();  // protect lw reuse in next half
    }

    // block reduce
#pragma unroll
    for (int off = 32; off > 0; off >>= 1) acc += __shfl_down(acc, off);
    if (lane == 0) lred[wid] = acc;
    __syncthreads();
    if (tid == 0) {
        float r = 0.0f;
        for (int w = 0; w < 16; ++w) r += lred[w];
        atomicAdd(out, r * (1.0f / NPROJ));
    }
}

extern "C" void kernel_launch(void* const* d_in, const int* in_sizes, int n_in,
                              void* d_out, int out_size, void* d_ws, size_t ws_size,
                              hipStream_t stream) {
    const float* X = (const float*)d_in[0];
    const float* Y = (const float*)d_in[1];
    const float* proj = (const float*)d_in[2];
    float* out = (float*)d_out;

    char* ws = (char*)d_ws;
    size_t off = 0;
    float* Xs = (float*)(ws + off);     off += (size_t)NB * HW * sizeof(float);
    float* Z = (float*)(ws + off);      off += (size_t)NB * HW * sizeof(float);
    float* Pmax = (float*)(ws + off);   off += NB * NCH * sizeof(float);
    int* Pidx = (int*)(ws + off);       off += NB * NCH * sizeof(int);
    float* Psx = (float*)(ws + off);    off += NB * NCH * sizeof(float);
    float* Psy = (float*)(ws + off);    off += NB * NCH * sizeof(float);

    partial_kernel<<<NB * NCH, 256, 0, stream>>>(X, Y, Xs, Pmax, Pidx, Psx, Psy, out);
    zprep_kernel<<<HW / 256, 256, 0, stream>>>(Pmax, Pidx, Psx, Psy, Xs, Y, Z);
    wproj_kernel<<<NPROJ, 1024, 0, stream>>>(proj, Z, out);
}